// Round 3
// baseline (873.833 us; speedup 1.0000x reference)
//
#include <hip/hip_runtime.h>
#include <hip/hip_bf16.h>
#include <stdint.h>

// ---------------------------------------------------------------------------
// HyperedgeEmbeddingExtractor: gather -> segment mean -> Linear -> LN -> GELU
// Pipeline:
//   k_zero   : zero begin/end arrays
//   k_bounds : segment boundaries from sorted seg_ids (scatter)
//   k_wsplit : split W fp32 -> bf16 hi/lo, pre-packed in MFMA B-fragment order
//   k_mean   : wave-per-edge gather + mean with 4-deep member pipeline,
//              bf16 hi/lo split written INTO d_out (row e = 2048 B:
//              512 hi shorts then 512 lo shorts)
//   k_gemm   : barrier-free bf16x3 MFMA GEMM (AhWh + AlWh + AhWl), A and B
//              fragments loaded global->VGPR directly (B pre-packed, L2-
//              resident; A rows L1-shared across waves), fused bias+LN+GELU.
// Workspace: ~2.9 MB (bounds + packed W splits).
// ---------------------------------------------------------------------------

typedef __attribute__((ext_vector_type(8))) short short8;
typedef __attribute__((ext_vector_type(4))) float f32x4;
typedef __attribute__((ext_vector_type(4))) unsigned short u16x4;

__device__ __forceinline__ unsigned short f2bf(float f) {
  __hip_bfloat16 h = __float2bfloat16(f);
  return __builtin_bit_cast(unsigned short, h);
}
__device__ __forceinline__ float bf2f(unsigned short u) {
  __hip_bfloat16 h = __builtin_bit_cast(__hip_bfloat16, u);
  return __bfloat162float(h);
}

// ---------------------------------------------------------------------------
__global__ void k_zero(int* __restrict__ beg, int* __restrict__ end_, int E) {
  int i = blockIdx.x * 256 + threadIdx.x;
  if (i < E) { beg[i] = 0; end_[i] = 0; }
}

__global__ void k_bounds(const int* __restrict__ seg, int* __restrict__ beg,
                         int* __restrict__ end_, int M) {
  int i = blockIdx.x * 256 + threadIdx.x;
  if (i >= M) return;
  int s = seg[i];
  if (i == 0 || seg[i - 1] != s) beg[s] = i;
  if (i == M - 1 || seg[i + 1] != s) end_[s] = i + 1;
}

// W[512][512] fp32 -> Whi/Wlo packed: page = (k>>3) (i.e. 4*kt+g), then
// [c(512)][j(8)], k = 32*kt + 8*g + j. Offset = (k>>3)*4096 + c*8 + (k&7).
__global__ void k_wsplit(const float* __restrict__ W, unsigned short* __restrict__ Whi,
                         unsigned short* __restrict__ Wlo) {
  int t = blockIdx.x * 256 + threadIdx.x;
  if (t >= 512 * 512) return;
  int k = t >> 9, c = t & 511;
  float w = W[t];
  unsigned short hi = f2bf(w);
  unsigned short lo = f2bf(w - bf2f(hi));
  int o = (k >> 3) * 4096 + c * 8 + (k & 7);
  Whi[o] = hi;
  Wlo[o] = lo;
}

// 4 edges per 256-thread block, one wave per edge. Lane l owns floats
// [4l,4l+4) and [256+4l,+4). Member loop unrolled x4 with prefetched indices
// -> 8 independent 1KB row-loads in flight. Output into a16 (= d_out).
__global__ void k_mean(const float* __restrict__ z, const int* __restrict__ midx,
                       const int* __restrict__ beg, const int* __restrict__ end_,
                       unsigned short* a16, int E) {
  const int w = threadIdx.x >> 6, l = threadIdx.x & 63;
  const int e = blockIdx.x * 4 + w;
  if (e >= E) return;
  const int b = beg[e], en = end_[e];
  const float* zl = z + l * 4;
  f32x4 a0 = {0.f, 0.f, 0.f, 0.f}, a1 = {0.f, 0.f, 0.f, 0.f};
  int m = b;
  for (; m + 4 <= en; m += 4) {
    const int r0 = midx[m], r1 = midx[m + 1], r2 = midx[m + 2], r3 = midx[m + 3];
    const f32x4 u0 = *(const f32x4*)(zl + (size_t)r0 * 512);
    const f32x4 u1 = *(const f32x4*)(zl + (size_t)r0 * 512 + 256);
    const f32x4 v0 = *(const f32x4*)(zl + (size_t)r1 * 512);
    const f32x4 v1 = *(const f32x4*)(zl + (size_t)r1 * 512 + 256);
    const f32x4 s0 = *(const f32x4*)(zl + (size_t)r2 * 512);
    const f32x4 s1 = *(const f32x4*)(zl + (size_t)r2 * 512 + 256);
    const f32x4 t0 = *(const f32x4*)(zl + (size_t)r3 * 512);
    const f32x4 t1 = *(const f32x4*)(zl + (size_t)r3 * 512 + 256);
    a0 += u0; a1 += u1; a0 += v0; a1 += v1;
    a0 += s0; a1 += s1; a0 += t0; a1 += t1;
  }
  for (; m < en; ++m) {
    const int r = midx[m];
    a0 += *(const f32x4*)(zl + (size_t)r * 512);
    a1 += *(const f32x4*)(zl + (size_t)r * 512 + 256);
  }
  const int cnt = en - b;
  const float den = 1.f / (float)(cnt > 0 ? cnt : 1);
  u16x4 h0, l0, h1, l1;
#pragma unroll
  for (int j = 0; j < 4; ++j) {
    const float m0 = a0[j] * den, m1 = a1[j] * den;
    h0[j] = f2bf(m0); l0[j] = f2bf(m0 - bf2f(h0[j]));
    h1[j] = f2bf(m1); l1[j] = f2bf(m1 - bf2f(h1[j]));
  }
  unsigned short* rowp = a16 + (size_t)e * 1024;
  *(u16x4*)(rowp + l * 4) = h0;
  *(u16x4*)(rowp + 256 + l * 4) = h1;
  *(u16x4*)(rowp + 512 + l * 4) = l0;
  *(u16x4*)(rowp + 768 + l * 4) = l1;
}

// ---------------------------------------------------------------------------
// GEMM: out[e][c] = GELU(LN(mean[e][:] @ W[:][c] + b[c]))
// block = 256 threads (4 waves), tile 64 rows x 512 cols; wave w owns cols
// [128w,128w+128), all 64 rows. acc[4 mf][8 nf] f32x4. K' = 3*512 (bf16x3),
// 3 passes x 16 chunks of K=32. NO LDS staging, NO barriers in the K-loop:
// fragments stream global->VGPR (B L2-resident, A L1-shared across waves),
// compiler pipelines with counted vmcnt.
// ---------------------------------------------------------------------------
__launch_bounds__(256, 2)
__global__ void k_gemm(const unsigned short* a16,
                       const unsigned short* __restrict__ Whi,
                       const unsigned short* __restrict__ Wlo,
                       const float* __restrict__ bias, const float* __restrict__ gamma,
                       const float* __restrict__ beta, float* out, int E) {
  __shared__ float lRed[64 * 4];
  __shared__ float lMu[64], lRs[64];

  const int t = threadIdx.x;
  const int w = t >> 6, l = t & 63;
  const int g = l >> 4, l15 = l & 15;
  const int cw = w * 128;
  const int e0 = blockIdx.x * 64;

  // per-lane A row pointers (rows clamped; clamped rows only feed outputs
  // that the er>=E guard discards)
  const unsigned short* pA[4];
#pragma unroll
  for (int mf = 0; mf < 4; ++mf) {
    int R = e0 + 16 * mf + l15;
    if (R > E - 1) R = E - 1;
    pA[mf] = a16 + (size_t)R * 1024 + g * 8;
  }
  // per-lane B base: page g, col cw+l15 (+16*nf later), chunk kt adds 4 pages
  const size_t bOff = (size_t)g * 4096 + (size_t)(cw + l15) * 8;

  f32x4 acc[4][8];
#pragma unroll
  for (int mf = 0; mf < 4; ++mf)
#pragma unroll
    for (int nf = 0; nf < 8; ++nf) acc[mf][nf] = (f32x4){0.f, 0.f, 0.f, 0.f};

  for (int p = 0; p < 3; ++p) {
    const unsigned short* pB = ((p == 2) ? Wlo : Whi) + bOff;
    const int poff = (p == 1) ? 512 : 0;  // Alo lives at +512 shorts
#pragma unroll 2
    for (int kt = 0; kt < 16; ++kt) {
      short8 af[4];
#pragma unroll
      for (int mf = 0; mf < 4; ++mf)
        af[mf] = *(const short8*)(pA[mf] + poff + kt * 32);
      short8 bf[8];
#pragma unroll
      for (int nf = 0; nf < 8; ++nf)
        bf[nf] = *(const short8*)(pB + (size_t)kt * 16384 + nf * 128);
#pragma unroll
      for (int nf = 0; nf < 8; ++nf)
#pragma unroll
        for (int mf = 0; mf < 4; ++mf)
          acc[mf][nf] = __builtin_amdgcn_mfma_f32_16x16x32_bf16(af[mf], bf[nf], acc[mf][nf], 0, 0, 0);
    }
  }

  // ---- epilogue: bias + LayerNorm + GELU (exact erf) ----
  float bia[8], gam[8], bet[8];
#pragma unroll
  for (int nf = 0; nf < 8; ++nf) {
    const int col = cw + 16 * nf + l15;
    bia[nf] = bias[col]; gam[nf] = gamma[col]; bet[nf] = beta[col];
  }
#pragma unroll
  for (int mf = 0; mf < 4; ++mf)
#pragma unroll
    for (int nf = 0; nf < 8; ++nf)
#pragma unroll
      for (int r = 0; r < 4; ++r) acc[mf][nf][r] += bia[nf];

  // mean: in-lane sum over 8 cols, 16-lane shfl reduce, cross-wave via LDS
  float s_[4][4];
#pragma unroll
  for (int mf = 0; mf < 4; ++mf)
#pragma unroll
    for (int r = 0; r < 4; ++r) {
      float v = 0.f;
#pragma unroll
      for (int nf = 0; nf < 8; ++nf) v += acc[mf][nf][r];
      v += __shfl_xor(v, 1); v += __shfl_xor(v, 2);
      v += __shfl_xor(v, 4); v += __shfl_xor(v, 8);
      s_[mf][r] = v;
    }
  if (l15 == 0) {
#pragma unroll
    for (int mf = 0; mf < 4; ++mf)
#pragma unroll
      for (int r = 0; r < 4; ++r) lRed[(16 * mf + 4 * g + r) * 4 + w] = s_[mf][r];
  }
  __syncthreads();
  if (t < 64) lMu[t] = (lRed[t * 4] + lRed[t * 4 + 1] + lRed[t * 4 + 2] + lRed[t * 4 + 3]) * (1.f / 512.f);
  __syncthreads();

  // variance
  float mu_[4][4];
#pragma unroll
  for (int mf = 0; mf < 4; ++mf)
#pragma unroll
    for (int r = 0; r < 4; ++r) mu_[mf][r] = lMu[16 * mf + 4 * g + r];
#pragma unroll
  for (int mf = 0; mf < 4; ++mf)
#pragma unroll
    for (int r = 0; r < 4; ++r) {
      float v = 0.f;
#pragma unroll
      for (int nf = 0; nf < 8; ++nf) {
        const float d = acc[mf][nf][r] - mu_[mf][r];
        v += d * d;
      }
      v += __shfl_xor(v, 1); v += __shfl_xor(v, 2);
      v += __shfl_xor(v, 4); v += __shfl_xor(v, 8);
      s_[mf][r] = v;
    }
  if (l15 == 0) {
#pragma unroll
    for (int mf = 0; mf < 4; ++mf)
#pragma unroll
      for (int r = 0; r < 4; ++r) lRed[(16 * mf + 4 * g + r) * 4 + w] = s_[mf][r];
  }
  __syncthreads();
  if (t < 64) {
    const float sse = lRed[t * 4] + lRed[t * 4 + 1] + lRed[t * 4 + 2] + lRed[t * 4 + 3];
    lRs[t] = rsqrtf(sse * (1.f / 512.f) + 1e-5f);
  }
  __syncthreads();

  // normalize + gamma/beta + exact GELU + store (overwrites the A rows we own)
#pragma unroll
  for (int mf = 0; mf < 4; ++mf)
#pragma unroll
    for (int r = 0; r < 4; ++r) {
      const int row = 16 * mf + 4 * g + r;
      const int er = e0 + row;
      if (er >= E) continue;
      const float mu = lMu[row], rs = lRs[row];
#pragma unroll
      for (int nf = 0; nf < 8; ++nf) {
        const int col = cw + 16 * nf + l15;
        const float x = (acc[mf][nf][r] - mu) * rs * gam[nf] + bet[nf];
        const float y = 0.5f * x * (1.f + erff(x * 0.70710678118654752f));
        out[(size_t)er * 512 + col] = y;
      }
    }
}

// ---------------------------------------------------------------------------
extern "C" void kernel_launch(void* const* d_in, const int* in_sizes, int n_in,
                              void* d_out, int out_size, void* d_ws, size_t ws_size,
                              hipStream_t stream) {
  const float* z = (const float*)d_in[0];
  const float* W = (const float*)d_in[1];
  const float* bias = (const float*)d_in[2];
  const float* gamma = (const float*)d_in[3];
  const float* beta = (const float*)d_in[4];
  const int* midx = (const int*)d_in[5];
  const int* seg = (const int*)d_in[6];
  const int M = in_sizes[5];
  const int E = out_size / 512;

  char* ws = (char*)d_ws;
  size_t off = 0;
  auto alloc = [&](size_t bytes) {
    void* p = ws + off;
    off = (off + bytes + 255) & ~(size_t)255;
    return p;
  };
  int* beg = (int*)alloc((size_t)E * 4);
  int* end_ = (int*)alloc((size_t)E * 4);
  unsigned short* Whi = (unsigned short*)alloc((size_t)512 * 512 * 2);
  unsigned short* Wlo = (unsigned short*)alloc((size_t)512 * 512 * 2);
  (void)ws_size; (void)n_in;

  unsigned short* a16 = (unsigned short*)d_out;   // A-buffer aliases the output

  k_zero<<<(E + 255) / 256, 256, 0, stream>>>(beg, end_, E);
  k_bounds<<<(M + 255) / 256, 256, 0, stream>>>(seg, beg, end_, M);
  k_wsplit<<<(512 * 512 + 255) / 256, 256, 0, stream>>>(W, Whi, Wlo);
  k_mean<<<(E + 3) / 4, 256, 0, stream>>>(z, midx, beg, end_, a16, E);
  k_gemm<<<(E + 63) / 64, 256, 0, stream>>>(a16, Whi, Wlo, bias, gamma, beta,
                                            (float*)d_out, E);
}